// Round 8
// baseline (532.566 us; speedup 1.0000x reference)
//
#include <hip/hip_runtime.h>

#define NS 1024   // spins / steps
#define NB 4096   // batch
#define NH 128    // hidden
#define RB 8      // batch rows per block (2 independent blocks/CU)
#define NT 256    // threads per block (4 waves, 2 hid-tiles each)
#define HLF (NS / 2)

typedef __attribute__((ext_vector_type(8))) short short8;
typedef __attribute__((ext_vector_type(4))) float f32x4;

__device__ __forceinline__ short f2bf(float x) {   // fp32 -> bf16 RNE
    unsigned u = __builtin_bit_cast(unsigned, x);
    u = (u + 0x7FFFu + ((u >> 16) & 1u)) >> 16;
    return (short)u;
}
__device__ __forceinline__ float vexp2(float x) {  // raw v_exp_f32 (2^x)
    float r;
    asm("v_exp_f32 %0, %1" : "=v"(r) : "v"(x));
    return r;
}

// LDS-only barrier: drain lgkm (h writes), NOT vmcnt — spin prefetch and out
// stores stay in flight across steps.
#define BARRIER() asm volatile("s_waitcnt lgkmcnt(0)\n\ts_barrier" ::: "memory")

__global__ __launch_bounds__(NT, 2)
void pwf_kernel(const float* __restrict__ data_in,
                const float* __restrict__ W_ih,
                const float* __restrict__ W_hh,
                const float* __restrict__ b_ih,
                const float* __restrict__ b_hh,
                const float* __restrict__ W_lin,
                const float* __restrict__ b_lin,
                float* __restrict__ out)
{
    // TRANSPOSED compute: D = W_hh · h^T. A = W_hh rows (static regs);
    // B = h (lane=batch, 8 real rows, cols 8..15 duplicate 0..7 = broadcast);
    // C: lane=batch, regs=4 consecutive hidden -> one b64 write per tile.
    // LDS: bf16 h, elem(batch b, hid) at b*128 + ((hid + 8*b) & 127) [shorts]
    __shared__ __align__(16) short hlds[2][RB * NH];   // 4 KB

    const int tid = threadIdx.x;
    const int w   = tid >> 6;       // wave 0..3 (owns hid-tiles w and w+4)
    const int l   = tid & 63;       // lane
    const int g   = l >> 4;         // k-group 0..3
    const int b   = l & 15;         // tile column
    const int br  = b & 7;          // real batch row (b>=8 duplicates)
    const int b0  = blockIdx.x * RB;
    const int LW  = blockIdx.x & 3; // logit/epilogue wave (spread across SIMDs)

    const float TL2E = 2.8853900817779268f;  // 2*log2(e)
    const float L2E  = 1.4426950408889634f;  // log2(e)

    // ---- A fragments: W_hh rows (exp2-domain), registers forever ----
    const int hrX = w * 16 + b;              // tile X output row
    const int hrY = hrX + 64;                // tile Y output row
    short8 aX[4], aY[4];
    #pragma unroll
    for (int kb = 0; kb < 4; ++kb) {
        const float* sx = W_hh + hrX * NH + kb * 32 + g * 8;
        const float* sy = W_hh + hrY * NH + kb * 32 + g * 8;
        short8 vx, vy;
        #pragma unroll
        for (int i = 0; i < 8; ++i) { vx[i] = f2bf(TL2E * sx[i]); vy[i] = f2bf(TL2E * sy[i]); }
        aX[kb] = vx; aY[kb] = vy;
    }
    // ---- logit A-fragment (wave LW): row 0 = log2e*(W_lin[1]-W_lin[0]) ----
    short8 lfrag[4];
    #pragma unroll
    for (int kb = 0; kb < 4; ++kb) {
        short8 v;
        #pragma unroll
        for (int i = 0; i < 8; ++i) {
            const int k = kb * 32 + g * 8 + i;
            v[i] = (b == 0) ? f2bf(L2E * (W_lin[NH + k] - W_lin[k])) : (short)0;
        }
        lfrag[kb] = v;
    }

    // ---- per-C-reg input contributions ----
    float cvX0[4], cvX1[4], cvY0[4], cvY1[4];
    #pragma unroll
    for (int r = 0; r < 4; ++r) {
        const int hx = w * 16 + 4 * g + r;
        const int hy = hx + 64;
        const float cbx = b_ih[hx] + b_hh[hx];
        const float cby = b_ih[hy] + b_hh[hy];
        cvX0[r] = TL2E * (W_ih[hx * 2 + 0] + cbx);
        cvX1[r] = TL2E * (W_ih[hx * 2 + 1] + cbx);
        cvY0[r] = TL2E * (W_ih[hy * 2 + 0] + cby);
        cvY1[r] = TL2E * (W_ih[hy * 2 + 1] + cby);
    }
    const float blD = L2E * (b_lin[1] - b_lin[0]);

    // ---- LDS offsets (shorts) ----
    int aoff[4];
    #pragma unroll
    for (int kb = 0; kb < 4; ++kb)
        aoff[kb] = br * NH + ((kb * 32 + g * 8 + 8 * br) & 127);
    const int woffX = br * NH + ((w * 16 + 4 * g + 8 * br) & 127);
    const int woffY = br * NH + ((w * 16 + 64 + 4 * g + 8 * br) & 127);

    // ---- init ----
    ((uint4*)hlds)[tid] = make_uint4(0u, 0u, 0u, 0u);   // 256*16B = both buffers
    int cntup = 0, cntdn = 0;
    int selp = 0;                        // input select (spin T-1); 0 = init [1,0]
    int ump = 0, dmp = 0;                // mask bits for out[T] (pre-consume state)
    float suA = data_in[(size_t)(b0 + br) * 2];            // spin 0
    float suB = data_in[((size_t)NB + b0 + br) * 2];       // spin 1
    float ediff = 0.0f;                  // saved logit-diff (out[T-2], wave LW)
    int eum = 0, edm = 0;
    BARRIER();

#define STEP(T, P, SU)                                                         \
    {                                                                          \
        const short* hr = hlds[P];                                             \
        short* hw = hlds[(P) ^ 1];                                             \
        const short8 h0 = *(const short8*)&hr[aoff[0]];                        \
        const short8 h1 = *(const short8*)&hr[aoff[1]];                        \
        const short8 h2 = *(const short8*)&hr[aoff[2]];                        \
        const short8 h3 = *(const short8*)&hr[aoff[3]];                        \
        if (w == LW) {                                                         \
            __builtin_amdgcn_s_setprio(1);                                     \
            if ((T) >= 2 && l < 8) {   /* deferred store out[T-2] */           \
                float p0 = __builtin_amdgcn_rcpf(1.0f + vexp2(ediff));         \
                float p1 = 1.0f - p0;                                          \
                if (eum) { p0 = 0.0f; p1 = 1.0f; }                             \
                if (edm) { p0 = 1.0f; p1 = 0.0f; }   /* down overrides */      \
                *(float2*)&out[((size_t)((T) - 2) * NB + b0 + l) * 2] =        \
                    make_float2(p0, p1);                                       \
            }                                                                  \
        }                                                                      \
        /* recurrence: 4 independent 2-deep MFMA chains (tiles X, Y) */        \
        f32x4 zz = {0.f, 0.f, 0.f, 0.f};                                       \
        f32x4 cX01 = __builtin_amdgcn_mfma_f32_16x16x32_bf16(aX[0], h0, zz, 0, 0, 0); \
        cX01 = __builtin_amdgcn_mfma_f32_16x16x32_bf16(aX[1], h1, cX01, 0, 0, 0); \
        f32x4 cX23 = __builtin_amdgcn_mfma_f32_16x16x32_bf16(aX[2], h2, zz, 0, 0, 0); \
        cX23 = __builtin_amdgcn_mfma_f32_16x16x32_bf16(aX[3], h3, cX23, 0, 0, 0); \
        f32x4 cY01 = __builtin_amdgcn_mfma_f32_16x16x32_bf16(aY[0], h0, zz, 0, 0, 0); \
        cY01 = __builtin_amdgcn_mfma_f32_16x16x32_bf16(aY[1], h1, cY01, 0, 0, 0); \
        f32x4 cY23 = __builtin_amdgcn_mfma_f32_16x16x32_bf16(aY[2], h2, zz, 0, 0, 0); \
        cY23 = __builtin_amdgcn_mfma_f32_16x16x32_bf16(aY[3], h3, cY23, 0, 0, 0); \
        if (w == LW && (T) >= 1) {     /* logit-diffs for out[T-1] */          \
            f32x4 d01 = __builtin_amdgcn_mfma_f32_16x16x32_bf16(lfrag[0], h0, zz, 0, 0, 0); \
            d01 = __builtin_amdgcn_mfma_f32_16x16x32_bf16(lfrag[1], h1, d01, 0, 0, 0); \
            f32x4 d23 = __builtin_amdgcn_mfma_f32_16x16x32_bf16(lfrag[2], h2, zz, 0, 0, 0); \
            d23 = __builtin_amdgcn_mfma_f32_16x16x32_bf16(lfrag[3], h3, d23, 0, 0, 0); \
            ediff = d01[0] + d23[0] + blD;    /* valid on lanes g==0 */        \
            eum = ump; edm = dmp;             /* masks for out[T-1] */         \
        }                                                                      \
        ump = (cntup >= HLF);   /* mask for out[T]: state after spins<T */     \
        dmp = (cntdn >= HLF);                                                  \
        float hnX[4], hnY[4];                                                  \
        _Pragma("unroll")                                                      \
        for (int r = 0; r < 4; ++r) {                                          \
            const float cvx = selp ? cvX1[r] : cvX0[r];                        \
            const float cvy = selp ? cvY1[r] : cvY0[r];                        \
            const float ex = vexp2(cX01[r] + cX23[r] + cvx);                   \
            const float ey = vexp2(cY01[r] + cY23[r] + cvy);                   \
            hnX[r] = fmaf(__builtin_amdgcn_rcpf(ex + 1.0f), -2.0f, 1.0f);      \
            hnY[r] = fmaf(__builtin_amdgcn_rcpf(ey + 1.0f), -2.0f, 1.0f);      \
        }                                                                      \
        {  /* consume spin T + prefetch spin T+2 */                            \
            const int isup = ((SU) > 0.5f) ? 1 : 0;                            \
            cntup += isup; cntdn += 1 - isup;                                  \
            selp = 1 - isup;                                                   \
            const int tn = ((T) + 2 < NS) ? (T) + 2 : NS - 1;                  \
            (SU) = data_in[((size_t)tn * NB + b0 + br) * 2];                   \
        }                                                                      \
        if (b < 8) {                                                           \
            unsigned pX01, pX23, pY01, pY23;                                   \
            asm("v_cvt_pk_bf16_f32 %0, %1, %2" : "=v"(pX01) : "v"(hnX[0]), "v"(hnX[1])); \
            asm("v_cvt_pk_bf16_f32 %0, %1, %2" : "=v"(pX23) : "v"(hnX[2]), "v"(hnX[3])); \
            asm("v_cvt_pk_bf16_f32 %0, %1, %2" : "=v"(pY01) : "v"(hnY[0]), "v"(hnY[1])); \
            asm("v_cvt_pk_bf16_f32 %0, %1, %2" : "=v"(pY23) : "v"(hnY[2]), "v"(hnY[3])); \
            *(uint2*)&hw[woffX] = make_uint2(pX01, pX23);                      \
            *(uint2*)&hw[woffY] = make_uint2(pY01, pY23);                      \
        }                                                                      \
        if (w == LW) __builtin_amdgcn_s_setprio(0);                            \
        BARRIER();                                                             \
    }

    for (int t = 0; t < NS; t += 2) {
        STEP(t, 0, suA)
        STEP(t + 1, 1, suB)
    }

    // ---- post-loop: flush out[NS-2]; out[NS-1] from h_NS (in hlds[0]) ----
    if (w == LW) {
        if (l < 8) {
            float p0 = __builtin_amdgcn_rcpf(1.0f + vexp2(ediff));
            float p1 = 1.0f - p0;
            if (eum) { p0 = 0.0f; p1 = 1.0f; }
            if (edm) { p0 = 1.0f; p1 = 0.0f; }
            *(float2*)&out[((size_t)(NS - 2) * NB + b0 + l) * 2] =
                make_float2(p0, p1);
        }
        const short* hr = hlds[0];
        const short8 h0 = *(const short8*)&hr[aoff[0]];
        const short8 h1 = *(const short8*)&hr[aoff[1]];
        const short8 h2 = *(const short8*)&hr[aoff[2]];
        const short8 h3 = *(const short8*)&hr[aoff[3]];
        f32x4 zz = {0.f, 0.f, 0.f, 0.f};
        f32x4 d01 = __builtin_amdgcn_mfma_f32_16x16x32_bf16(lfrag[0], h0, zz, 0, 0, 0);
        d01 = __builtin_amdgcn_mfma_f32_16x16x32_bf16(lfrag[1], h1, d01, 0, 0, 0);
        f32x4 d23 = __builtin_amdgcn_mfma_f32_16x16x32_bf16(lfrag[2], h2, zz, 0, 0, 0);
        d23 = __builtin_amdgcn_mfma_f32_16x16x32_bf16(lfrag[3], h3, d23, 0, 0, 0);
        const float fdiff = d01[0] + d23[0] + blD;
        if (l < 8) {
            float p0 = __builtin_amdgcn_rcpf(1.0f + vexp2(fdiff));
            float p1 = 1.0f - p0;
            if (ump) { p0 = 0.0f; p1 = 1.0f; }
            if (dmp) { p0 = 1.0f; p1 = 0.0f; }
            *(float2*)&out[((size_t)(NS - 1) * NB + b0 + l) * 2] =
                make_float2(p0, p1);
        }
    }
}

extern "C" void kernel_launch(void* const* d_in, const int* in_sizes, int n_in,
                              void* d_out, int out_size, void* d_ws, size_t ws_size,
                              hipStream_t stream) {
    const float* data_in = (const float*)d_in[0];
    const float* W_ih    = (const float*)d_in[1];
    const float* W_hh    = (const float*)d_in[2];
    const float* b_ih    = (const float*)d_in[3];
    const float* b_hh    = (const float*)d_in[4];
    const float* W_lin   = (const float*)d_in[5];
    const float* b_lin   = (const float*)d_in[6];
    float* out = (float*)d_out;

    dim3 grid(NB / RB);   // 512 blocks -> 2 independent (desync) blocks per CU
    dim3 block(NT);       // 4 waves
    pwf_kernel<<<grid, block, 0, stream>>>(data_in, W_ih, W_hh, b_ih, b_hh,
                                           W_lin, b_lin, out);
}